// Round 9
// baseline (82.582 us; speedup 1.0000x reference)
//
#include <hip/hip_runtime.h>

#define NN 100000
#define NE 1600000
#define HIDN 256
#define OD0 20000
#define OD1 1881
#define OD2 27000
#define OUT_TOTAL (OD0 + OD1 + OD2)
#define NB_OUT ((OUT_TOTAL + 63) / 64)

// caps (expected: nL1 ~48, nS1 ~51, nL2 ~820, nS2 ~900)
#define MAXL1 8192
#define MAXS1 112
#define MAXL2 65536
#define MAXS2 8192

#define MASKW 3200       // ceil(100000/32)=3125, padded
#define XB_LIST 1024     // per-row match-list cap in k_x1agg

__device__ __forceinline__ float wave_sum64(float v) {
#pragma unroll
    for (int off = 32; off >= 1; off >>= 1) v += __shfl_xor(v, off, 64);
    return v;
}

__device__ __forceinline__ void insert_set(unsigned* mask, int* cnt, int cap,
                                           int* slot, int* list, int n) {
    unsigned bit = 1u << (n & 31);
    unsigned old = atomicOr(&mask[n >> 5], bit);
    if (!(old & bit)) {
        int s = atomicAdd(cnt, 1);
        if (s < cap) { slot[n] = s; list[s] = n; }
    }
}

// ---- 1: zero [cnts | mask1 | mask2 | degc | agg2] (contiguous, int4)
__global__ void k_init(int4* base, int n4) {
    int i = blockIdx.x * blockDim.x + threadIdx.x;
    int4 z = make_int4(0, 0, 0, 0);
    for (; i < n4; i += gridDim.x * blockDim.x) base[i] = z;
}

// ---- 2: collect edges with col<3 -> L1; build S1 = {0,1,2} U rows(L1) inline
__global__ __launch_bounds__(256) void k_scan1(
        const int* __restrict__ erow, const int* __restrict__ ecol,
        int* __restrict__ cnts, unsigned* __restrict__ mask1,
        int* __restrict__ slot1, int* __restrict__ S1, int2* __restrict__ L1) {
    int gid = blockIdx.x * blockDim.x + threadIdx.x;
    if (gid < 3) insert_set(mask1, &cnts[1], MAXS1, slot1, S1, gid);
    for (int i = gid; i < NE / 4; i += gridDim.x * blockDim.x) {
        int4 c4 = ((const int4*)ecol)[i];
        int cs[4] = {c4.x, c4.y, c4.z, c4.w};
#pragma unroll
        for (int u = 0; u < 4; u++) {
            if (cs[u] < 3) {
                int r = erow[i * 4 + u];
                int idx = atomicAdd(&cnts[0], 1);
                if (idx < MAXL1) L1[idx] = make_int2(r, cs[u]);
                insert_set(mask1, &cnts[1], MAXS1, slot1, S1, r);
            }
        }
    }
}

// ---- 3: collect edges with col in S1 -> L2; build S2 = rows(L2) U S1 inline
__global__ __launch_bounds__(256) void k_scan2(
        const int* __restrict__ erow, const int* __restrict__ ecol,
        int* __restrict__ cnts, const unsigned* __restrict__ mask1,
        unsigned* __restrict__ mask2, int* __restrict__ slot2,
        int* __restrict__ S2, const int* __restrict__ S1, int2* __restrict__ L2) {
    int gid = blockIdx.x * blockDim.x + threadIdx.x;
    int ns1 = min(cnts[1], MAXS1);
    if (gid < ns1) insert_set(mask2, &cnts[3], MAXS2, slot2, S2, S1[gid]);
    for (int i = gid; i < NE / 4; i += gridDim.x * blockDim.x) {
        int4 c4 = ((const int4*)ecol)[i];
        int cs[4] = {c4.x, c4.y, c4.z, c4.w};
#pragma unroll
        for (int u = 0; u < 4; u++) {
            int c = cs[u];
            if (mask1[c >> 5] & (1u << (c & 31))) {
                int r = erow[i * 4 + u];
                int idx = atomicAdd(&cnts[2], 1);
                if (idx < MAXL2) L2[idx] = make_int2(r, c);
                insert_set(mask2, &cnts[3], MAXS2, slot2, S2, r);
            }
        }
    }
}

// ---- 4: degree scan (S2 members only) + attention/LN0/h1 over S2, fused
#define DX_GRID 256
__global__ __launch_bounds__(256) void k_degx0(
        const int* __restrict__ cnts, const int* __restrict__ ecol,
        const unsigned* __restrict__ mask2, const int* __restrict__ slot2,
        int* __restrict__ degc,
        const int* __restrict__ S2, const float* __restrict__ latent,
        const float* __restrict__ wq, const float* __restrict__ bq,
        const float* __restrict__ wk, const float* __restrict__ bk,
        const float* __restrict__ wv, const float* __restrict__ bv,
        const float* __restrict__ ln0w, const float* __restrict__ ln0b,
        const float* __restrict__ g1w,
        float* __restrict__ x0c, float* __restrict__ h1c) {
    __shared__ float lw[3 * 4096];
    int t = threadIdx.x, b = blockIdx.x;
    int gid = b * 256 + t;
    {
        const float4* s0 = (const float4*)wq;
        const float4* s1 = (const float4*)wk;
        const float4* s2 = (const float4*)wv;
        float4* d0 = (float4*)&lw[0];
        float4* d1 = (float4*)&lw[4096];
        float4* d2 = (float4*)&lw[8192];
        for (int i = t; i < 1024; i += 256) { d0[i] = s0[i]; d1[i] = s1[i]; d2[i] = s2[i]; }
    }
    for (int i = gid; i < NE / 4; i += DX_GRID * 256) {
        int4 c4 = ((const int4*)ecol)[i];
        int cs[4] = {c4.x, c4.y, c4.z, c4.w};
#pragma unroll
        for (int u = 0; u < 4; u++) {
            int c = cs[u];
            if (mask2[c >> 5] & (1u << (c & 31))) {
                int s = slot2[c];
                if ((unsigned)s < MAXS2) atomicAdd(&degc[s], 1);
            }
        }
    }
    __syncthreads();
    int lane = t & 63, wid = t >> 6;
    int nS2 = min(cnts[3], MAXS2);
    for (int s = b * 4 + wid; s < nS2; s += DX_GRID * 4) {
        int n = S2[s];
        float xv = latent[n * 64 + lane];
        float aq = bq[lane], ak = bk[lane], av = bv[lane];
#pragma unroll
        for (int j = 0; j < 64; j++) {
            float xj = __shfl(xv, j, 64);
            aq = fmaf(xj, lw[j * 64 + lane], aq);
            ak = fmaf(xj, lw[4096 + j * 64 + lane], ak);
            av = fmaf(xj, lw[8192 + j * 64 + lane], av);
        }
        int d = lane & 15;
        float sj[4];
#pragma unroll
        for (int j = 0; j < 4; j++) {
            float kv = __shfl(ak, (j << 4) | d, 64);
            float pp = aq * kv;
            pp += __shfl_xor(pp, 1, 64); pp += __shfl_xor(pp, 2, 64);
            pp += __shfl_xor(pp, 4, 64); pp += __shfl_xor(pp, 8, 64);
            sj[j] = pp * 0.25f;
        }
        float mx = fmaxf(fmaxf(sj[0], sj[1]), fmaxf(sj[2], sj[3]));
        float e0 = expf(sj[0] - mx), e1 = expf(sj[1] - mx);
        float e2 = expf(sj[2] - mx), e3 = expf(sj[3] - mx);
        float inv = 1.f / (e0 + e1 + e2 + e3);
        float at[4] = {e0 * inv, e1 * inv, e2 * inv, e3 * inv};
        float o = 0.f;
#pragma unroll
        for (int j = 0; j < 4; j++) {
            float vv = __shfl(av, (j << 4) | d, 64);
            o = fmaf(at[j], vv, o);
        }
        float sum = wave_sum64(o), sq = wave_sum64(o * o);
        float mean = sum * (1.f / 64.f);
        float var = sq * (1.f / 64.f) - mean * mean;
        float x0 = (o - mean) * rsqrtf(var + 1e-5f) * ln0w[lane] + ln0b[lane];
        x0c[s * 64 + lane] = x0;
        float h = 0.f;
#pragma unroll
        for (int j = 0; j < 64; j++) {
            float xj = __shfl(x0, j, 64);
            h = fmaf(xj, g1w[j * 64 + lane], h);
        }
        h1c[s * 64 + lane] = h;
    }
}

// ---- 5: one block per S1 row: match list -> parallel gather -> x1 -> h2 ->
//          agg2 contributions; LAST finished block finalizes x2 + hg.
__global__ __launch_bounds__(256) void k_x1agg(
        const int* __restrict__ cnts, const int2* __restrict__ L1,
        const int2* __restrict__ L2, const int* __restrict__ S1,
        const int* __restrict__ slot1, const int* __restrict__ slot2,
        const int* __restrict__ degc,
        const float* __restrict__ x0c, const float* __restrict__ h1c,
        const float* __restrict__ g1b, const float* __restrict__ ln1w,
        const float* __restrict__ ln1b, const float* __restrict__ g2w,
        float* __restrict__ agg2, float* __restrict__ x1c3,
        const float* __restrict__ g2b, const float* __restrict__ ln2w,
        const float* __restrict__ ln2b,
        const float* __restrict__ w10, const float* __restrict__ b10,
        const float* __restrict__ w11, const float* __restrict__ b11,
        const float* __restrict__ w12, const float* __restrict__ b12,
        float* __restrict__ hg, int* __restrict__ done) {
    __shared__ int   s_cnt;
    __shared__ int   s_ea[XB_LIST];
    __shared__ float s_ew[XB_LIST];
    __shared__ float s_part[4][64];
    __shared__ int   s_last;
    __shared__ float s_x2f[192];
    int t = threadIdx.x, lane = t & 63, wid = t >> 6, b = blockIdx.x;
    int nl1 = min(cnts[0], MAXL1);
    int ns1 = min(cnts[1], MAXS1);
    int nl2 = min(cnts[2], MAXL2);
    bool active = (b < ns1);
    if (active) {
        if (t == 0) s_cnt = 0;
        s_part[wid][lane] = 0.f;
        __syncthreads();
        int n = S1[b];                   // this block's node
        int sc2 = slot2[n];              // its S2 slot (S1 subset of S2)
        float dc = rsqrtf((float)(degc[sc2] + 1));
        // resolve: thread-parallel scan of L2 + S1 self-loops, compact matches
        int ntot = nl2 + ns1;
        for (int e = t; e < ntot; e += 256) {
            int r; bool match;
            if (e < nl2) { int2 rc = L2[e]; r = rc.x; match = (slot1[rc.y] == b); }
            else         { r = S1[e - nl2]; match = (e - nl2 == b); }   // self loop
            if (match) {
                int a = slot2[r];
                if ((unsigned)a < MAXS2) {
                    float w = rsqrtf((float)(degc[a] + 1)) * dc;
                    int m = atomicAdd(&s_cnt, 1);
                    if (m < XB_LIST) { s_ea[m] = a; s_ew[m] = w; }
                }
            }
        }
        __syncthreads();
        // accumulate: 4 waves, independent coalesced gathers, wave-private partials
        int cm = min(s_cnt, XB_LIST);
        for (int m = wid; m < cm; m += 4)
            s_part[wid][lane] += h1c[s_ea[m] * 64 + lane] * s_ew[m];
        __syncthreads();
        if (wid == 0) {
            float agg = s_part[0][lane] + s_part[1][lane] + s_part[2][lane] + s_part[3][lane];
            float v = x0c[sc2 * 64 + lane] + agg + g1b[lane];
            float sum = wave_sum64(v), sq = wave_sum64(v * v);
            float mean = sum * (1.f / 64.f);
            float var = sq * (1.f / 64.f) - mean * mean;
            float x1 = (v - mean) * rsqrtf(var + 1e-5f) * ln1w[lane] + ln1b[lane];
            if (n < 3) x1c3[n * 64 + lane] = x1;
            // h2 = x1 @ gcn2_w (row-local)
            float h = 0.f;
#pragma unroll
            for (int j = 0; j < 64; j++) {
                float xj = __shfl(x1, j, 64);
                h = fmaf(xj, g2w[j * 64 + lane], h);
            }
            // agg2 contributions: edges in L1 (+{0,1,2} self-loops) whose row == n
            int ntot2 = nl1 + 3;
            for (int e0 = 0; e0 < ntot2; e0 += 64) {
                int e = e0 + lane;
                int match = 0, cc = 0; float wgt = 0.f;
                if (e < ntot2) {
                    int r, c;
                    if (e < nl1) { int2 rc = L1[e]; r = rc.x; c = rc.y; }
                    else { r = c = e - nl1; }   // self loops for 0,1,2
                    if (slot1[r] == b) {
                        int sr2 = slot2[r], scc2 = slot2[c];
                        if ((unsigned)sr2 < MAXS2 && (unsigned)scc2 < MAXS2) {
                            wgt = rsqrtf((float)(degc[sr2] + 1)) * rsqrtf((float)(degc[scc2] + 1));
                            match = 1; cc = c;
                        }
                    }
                }
                unsigned long long msk = __ballot(match);
                while (msk) {
                    int j = __ffsll((unsigned long long)msk) - 1;
                    msk &= msk - 1;
                    int cj = __shfl(cc, j, 64);
                    float wj = __shfl(wgt, j, 64);
                    atomicAdd(&agg2[cj * 64 + lane], h * wj);
                }
            }
        }
        __syncthreads();
    }
    // ---- all blocks: signal completion; last block finalizes x2 + hg
    __threadfence();
    if (t == 0) {
        int v = atomicAdd(done, 1);
        s_last = (v == (int)gridDim.x - 1) ? 1 : 0;
    }
    __syncthreads();
    if (!s_last) return;
    __threadfence();   // acquire: all writers' stores visible
    if (wid < 3) {
        float v = x1c3[wid * 64 + lane] + agg2[wid * 64 + lane] + g2b[lane];
        float sum = wave_sum64(v), sq = wave_sum64(v * v);
        float mean = sum * (1.f / 64.f);
        float var = sq * (1.f / 64.f) - mean * mean;
        s_x2f[wid * 64 + lane] = (v - mean) * rsqrtf(var + 1e-5f) * ln2w[lane] + ln2b[lane];
    }
    __syncthreads();
    {
        const float* W1[3] = {w10, w11, w12};
        const float* B1[3] = {b10, b11, b12};
#pragma unroll
        for (int gi = 0; gi < 3; gi++) {
            float acc = B1[gi][t];
#pragma unroll
            for (int j = 0; j < 64; j++) acc = fmaf(s_x2f[gi * 64 + j], W1[gi][j * 256 + t], acc);
            hg[gi * 256 + t] = fmaxf(acc, 0.f);
        }
    }
}

// ---- 6: lean split-K GEMV: 4 waves x 64 cols per block
__global__ __launch_bounds__(256) void k_gemv(const float* __restrict__ hg,
        const float* __restrict__ w20, const float* __restrict__ b20,
        const float* __restrict__ w21, const float* __restrict__ b21,
        const float* __restrict__ w22, const float* __restrict__ b22,
        float* __restrict__ out) {
    __shared__ float lh[768];
    __shared__ float part[256];
    int t = threadIdx.x;
    lh[t] = hg[t]; lh[t + 256] = hg[t + 256]; lh[t + 512] = hg[t + 512];
    __syncthreads();
    int tx = t & 63, ty = t >> 6;
    int o = blockIdx.x * 64 + tx;
    int gi = -1, jj = 0, od = 1;
    const float* w2 = w20;
    if (o < OD0)                 { gi = 0; jj = o;             od = OD0; w2 = w20; }
    else if (o < OD0 + OD1)      { gi = 1; jj = o - OD0;       od = OD1; w2 = w21; }
    else if (o < OUT_TOTAL)      { gi = 2; jj = o - OD0 - OD1; od = OD2; w2 = w22; }
    float acc = 0.f;
    if (gi >= 0) {
        const float* h = &lh[gi * 256 + ty * 64];
        const float* wp = &w2[(size_t)(ty * 64) * od + jj];
#pragma unroll 16
        for (int k = 0; k < 64; k++) acc = fmaf(h[k], wp[(size_t)k * od], acc);
    }
    part[t] = acc;
    __syncthreads();
    if (t < 64 && gi >= 0) {
        float r = part[t] + part[t + 64] + part[t + 128] + part[t + 192];
        const float* b2 = (gi == 0) ? b20 : (gi == 1) ? b21 : b22;
        out[o] = r + b2[jj];
    }
}

extern "C" void kernel_launch(void* const* d_in, const int* in_sizes, int n_in,
                              void* d_out, int out_size, void* d_ws, size_t ws_size,
                              hipStream_t stream) {
    (void)in_sizes; (void)n_in; (void)out_size; (void)ws_size;
    const float* latent = (const float*)d_in[0];
    const int*   edges  = (const int*)d_in[1];
    const float* wq  = (const float*)d_in[2];
    const float* bq  = (const float*)d_in[3];
    const float* wk  = (const float*)d_in[4];
    const float* bk  = (const float*)d_in[5];
    const float* wv  = (const float*)d_in[6];
    const float* bv  = (const float*)d_in[7];
    const float* ln0w = (const float*)d_in[8];
    const float* ln0b = (const float*)d_in[9];
    const float* g1w  = (const float*)d_in[10];
    const float* g1b  = (const float*)d_in[11];
    const float* ln1w = (const float*)d_in[12];
    const float* ln1b = (const float*)d_in[13];
    const float* g2w  = (const float*)d_in[14];
    const float* g2b  = (const float*)d_in[15];
    const float* ln2w = (const float*)d_in[16];
    const float* ln2b = (const float*)d_in[17];
    const float* gw1_0 = (const float*)d_in[18];
    const float* gb1_0 = (const float*)d_in[19];
    const float* gw2_0 = (const float*)d_in[20];
    const float* gb2_0 = (const float*)d_in[21];
    const float* gw1_1 = (const float*)d_in[22];
    const float* gb1_1 = (const float*)d_in[23];
    const float* gw2_1 = (const float*)d_in[24];
    const float* gb2_1 = (const float*)d_in[25];
    const float* gw1_2 = (const float*)d_in[26];
    const float* gb1_2 = (const float*)d_in[27];
    const float* gw2_2 = (const float*)d_in[28];
    const float* gb2_2 = (const float*)d_in[29];

    // workspace carve: [cnts|mask1|mask2|degc|agg2] = zero region
    char* ptr = (char*)d_ws;
    auto alloc = [&](size_t bytes) { char* r = ptr; ptr += (bytes + 255) & ~(size_t)255; return r; };
    int*      cnts  = (int*)alloc(64 * 4);        // [0]=nL1 [1]=nS1 [2]=nL2 [3]=nS2 [8]=done
    unsigned* mask1 = (unsigned*)alloc(MASKW * 4);
    unsigned* mask2 = (unsigned*)alloc(MASKW * 4);
    int*      degc  = (int*)alloc((size_t)MAXS2 * 4);
    float*    agg2  = (float*)alloc(192 * 4);
    char*     zero_end = ptr;
    int*      slot1 = (int*)alloc((size_t)NN * 4);   // valid only where mask1 bit set
    int*      slot2 = (int*)alloc((size_t)NN * 4);   // valid only where mask2 bit set
    int2*     L1    = (int2*)alloc((size_t)MAXL1 * 8);
    int*      S1    = (int*)alloc((size_t)MAXS1 * 4);
    int2*     L2    = (int2*)alloc((size_t)MAXL2 * 8);
    int*      S2    = (int*)alloc((size_t)MAXS2 * 4);
    float*    x0c   = (float*)alloc((size_t)MAXS2 * 64 * 4);
    float*    h1c   = (float*)alloc((size_t)MAXS2 * 64 * 4);
    float*    x1c3  = (float*)alloc(192 * 4);
    float*    hg    = (float*)alloc(3 * HIDN * 4);

    const int* erow = edges;
    const int* ecol = edges + NE;
    int zero_n4 = (int)((zero_end - (char*)cnts) / 16);

    const int SCAN_GRID = (NE / 4 + 255) / 256;
    k_init<<<16, 256, 0, stream>>>((int4*)cnts, zero_n4);
    k_scan1<<<SCAN_GRID, 256, 0, stream>>>(erow, ecol, cnts, mask1, slot1, S1, L1);
    k_scan2<<<SCAN_GRID, 256, 0, stream>>>(erow, ecol, cnts, mask1, mask2, slot2, S2, S1, L2);
    k_degx0<<<DX_GRID, 256, 0, stream>>>(cnts, ecol, mask2, slot2, degc, S2, latent,
                                         wq, bq, wk, bk, wv, bv, ln0w, ln0b, g1w, x0c, h1c);
    k_x1agg<<<MAXS1, 256, 0, stream>>>(cnts, L1, L2, S1, slot1, slot2, degc, x0c, h1c,
                                       g1b, ln1w, ln1b, g2w, agg2, x1c3,
                                       g2b, ln2w, ln2b,
                                       gw1_0, gb1_0, gw1_1, gb1_1, gw1_2, gb1_2,
                                       hg, &cnts[8]);
    k_gemv<<<NB_OUT, 256, 0, stream>>>(hg, gw2_0, gb2_0, gw2_1, gb2_1, gw2_2, gb2_2,
                                       (float*)d_out);
}

// Round 10
// 79.235 us; speedup vs baseline: 1.0423x; 1.0423x over previous
//
#include <hip/hip_runtime.h>

#define NN 100000
#define NE 1600000
#define HIDN 256
#define OD0 20000
#define OD1 1881
#define OD2 27000
#define OUT_TOTAL (OD0 + OD1 + OD2)
#define NB_OUT ((OUT_TOTAL + 63) / 64)

// caps (expected: nL1 ~48, nS1 ~51, nL2 ~820, nS2 ~900)
#define MAXL1 8192
#define MAXS1 112
#define MAXL2 65536
#define MAXS2 8192

#define MASKW 3200       // ceil(100000/32)=3125, padded
#define XB_LIST 1024     // per-row match-list cap in k_x1agg
#define NQ (NE / 8)      // 200000 int4's per stream, 2 streams

__device__ __forceinline__ float wave_sum64(float v) {
#pragma unroll
    for (int off = 32; off >= 1; off >>= 1) v += __shfl_xor(v, off, 64);
    return v;
}

__device__ __forceinline__ void insert_set(unsigned* mask, int* cnt, int cap,
                                           int* slot, int* list, int n) {
    unsigned bit = 1u << (n & 31);
    unsigned old = atomicOr(&mask[n >> 5], bit);
    if (!(old & bit)) {
        int s = atomicAdd(cnt, 1);
        if (s < cap) { slot[n] = s; list[s] = n; }
    }
}

// ---- 1: zero [cnts | mask1 | mask2 | degc | agg2] (contiguous, int4)
__global__ void k_init(int4* base, int n4) {
    int i = blockIdx.x * blockDim.x + threadIdx.x;
    int4 z = make_int4(0, 0, 0, 0);
    for (; i < n4; i += gridDim.x * blockDim.x) base[i] = z;
}

// ---- 2: collect edges with col<3 -> L1; build S1 = {0,1,2} U rows(L1) inline
//         two independent int4 streams per thread for 2x MLP
__global__ __launch_bounds__(256) void k_scan1(
        const int* __restrict__ erow, const int* __restrict__ ecol,
        int* __restrict__ cnts, unsigned* __restrict__ mask1,
        int* __restrict__ slot1, int* __restrict__ S1, int2* __restrict__ L1) {
    int gid = blockIdx.x * blockDim.x + threadIdx.x;
    int nth = gridDim.x * blockDim.x;
    if (gid < 3) insert_set(mask1, &cnts[1], MAXS1, slot1, S1, gid);
    const int4* ecol4 = (const int4*)ecol;
    for (int i = gid; i < NQ; i += nth) {
        int4 a = ecol4[i];
        int4 b = ecol4[i + NQ];
        int ca[4] = {a.x, a.y, a.z, a.w};
        int cb[4] = {b.x, b.y, b.z, b.w};
#pragma unroll
        for (int u = 0; u < 4; u++) {
            if (ca[u] < 3) {
                int r = erow[i * 4 + u];
                int idx = atomicAdd(&cnts[0], 1);
                if (idx < MAXL1) L1[idx] = make_int2(r, ca[u]);
                insert_set(mask1, &cnts[1], MAXS1, slot1, S1, r);
            }
            if (cb[u] < 3) {
                int r = erow[(i + NQ) * 4 + u];
                int idx = atomicAdd(&cnts[0], 1);
                if (idx < MAXL1) L1[idx] = make_int2(r, cb[u]);
                insert_set(mask1, &cnts[1], MAXS1, slot1, S1, r);
            }
        }
    }
}

// ---- 3: collect edges with col in S1 -> L2; build S2 = rows(L2) U S1 inline
__global__ __launch_bounds__(256) void k_scan2(
        const int* __restrict__ erow, const int* __restrict__ ecol,
        int* __restrict__ cnts, const unsigned* __restrict__ mask1,
        unsigned* __restrict__ mask2, int* __restrict__ slot2,
        int* __restrict__ S2, const int* __restrict__ S1, int2* __restrict__ L2) {
    int gid = blockIdx.x * blockDim.x + threadIdx.x;
    int nth = gridDim.x * blockDim.x;
    int ns1 = min(cnts[1], MAXS1);
    if (gid < ns1) insert_set(mask2, &cnts[3], MAXS2, slot2, S2, S1[gid]);
    const int4* ecol4 = (const int4*)ecol;
    for (int i = gid; i < NQ; i += nth) {
        int4 a = ecol4[i];
        int4 b = ecol4[i + NQ];
        int ca[4] = {a.x, a.y, a.z, a.w};
        int cb[4] = {b.x, b.y, b.z, b.w};
#pragma unroll
        for (int u = 0; u < 4; u++) {
            if (mask1[ca[u] >> 5] & (1u << (ca[u] & 31))) {
                int r = erow[i * 4 + u];
                int idx = atomicAdd(&cnts[2], 1);
                if (idx < MAXL2) L2[idx] = make_int2(r, ca[u]);
                insert_set(mask2, &cnts[3], MAXS2, slot2, S2, r);
            }
            if (mask1[cb[u] >> 5] & (1u << (cb[u] & 31))) {
                int r = erow[(i + NQ) * 4 + u];
                int idx = atomicAdd(&cnts[2], 1);
                if (idx < MAXL2) L2[idx] = make_int2(r, cb[u]);
                insert_set(mask2, &cnts[3], MAXS2, slot2, S2, r);
            }
        }
    }
}

// ---- 4: degree scan (S2 members only) + attention/LN0/h1 over S2, fused
//         weights read direct from global (L2-broadcast), no LDS staging
#define DX_GRID 256
__global__ __launch_bounds__(256) void k_degx0(
        const int* __restrict__ cnts, const int* __restrict__ ecol,
        const unsigned* __restrict__ mask2, const int* __restrict__ slot2,
        int* __restrict__ degc,
        const int* __restrict__ S2, const float* __restrict__ latent,
        const float* __restrict__ wq, const float* __restrict__ bq,
        const float* __restrict__ wk, const float* __restrict__ bk,
        const float* __restrict__ wv, const float* __restrict__ bv,
        const float* __restrict__ ln0w, const float* __restrict__ ln0b,
        const float* __restrict__ g1w,
        float* __restrict__ x0c, float* __restrict__ h1c) {
    int t = threadIdx.x, b = blockIdx.x;
    int gid = b * 256 + t;
    const int4* ecol4 = (const int4*)ecol;
    for (int i = gid; i < NQ; i += DX_GRID * 256) {
        int4 a = ecol4[i];
        int4 bb = ecol4[i + NQ];
        int ca[4] = {a.x, a.y, a.z, a.w};
        int cb[4] = {bb.x, bb.y, bb.z, bb.w};
#pragma unroll
        for (int u = 0; u < 4; u++) {
            if (mask2[ca[u] >> 5] & (1u << (ca[u] & 31))) {
                int s = slot2[ca[u]];
                if ((unsigned)s < MAXS2) atomicAdd(&degc[s], 1);
            }
            if (mask2[cb[u] >> 5] & (1u << (cb[u] & 31))) {
                int s = slot2[cb[u]];
                if ((unsigned)s < MAXS2) atomicAdd(&degc[s], 1);
            }
        }
    }
    int lane = t & 63, wid = t >> 6;
    int nS2 = min(cnts[3], MAXS2);
    for (int s = b * 4 + wid; s < nS2; s += DX_GRID * 4) {
        int n = S2[s];
        float xv = latent[n * 64 + lane];
        float aq = bq[lane], ak = bk[lane], av = bv[lane];
#pragma unroll
        for (int j = 0; j < 64; j++) {
            float xj = __shfl(xv, j, 64);
            aq = fmaf(xj, wq[j * 64 + lane], aq);
            ak = fmaf(xj, wk[j * 64 + lane], ak);
            av = fmaf(xj, wv[j * 64 + lane], av);
        }
        int d = lane & 15;
        float sj[4];
#pragma unroll
        for (int j = 0; j < 4; j++) {
            float kv = __shfl(ak, (j << 4) | d, 64);
            float pp = aq * kv;
            pp += __shfl_xor(pp, 1, 64); pp += __shfl_xor(pp, 2, 64);
            pp += __shfl_xor(pp, 4, 64); pp += __shfl_xor(pp, 8, 64);
            sj[j] = pp * 0.25f;
        }
        float mx = fmaxf(fmaxf(sj[0], sj[1]), fmaxf(sj[2], sj[3]));
        float e0 = expf(sj[0] - mx), e1 = expf(sj[1] - mx);
        float e2 = expf(sj[2] - mx), e3 = expf(sj[3] - mx);
        float inv = 1.f / (e0 + e1 + e2 + e3);
        float at[4] = {e0 * inv, e1 * inv, e2 * inv, e3 * inv};
        float o = 0.f;
#pragma unroll
        for (int j = 0; j < 4; j++) {
            float vv = __shfl(av, (j << 4) | d, 64);
            o = fmaf(at[j], vv, o);
        }
        float sum = wave_sum64(o), sq = wave_sum64(o * o);
        float mean = sum * (1.f / 64.f);
        float var = sq * (1.f / 64.f) - mean * mean;
        float x0 = (o - mean) * rsqrtf(var + 1e-5f) * ln0w[lane] + ln0b[lane];
        x0c[s * 64 + lane] = x0;
        float h = 0.f;
#pragma unroll
        for (int j = 0; j < 64; j++) {
            float xj = __shfl(x0, j, 64);
            h = fmaf(xj, g1w[j * 64 + lane], h);
        }
        h1c[s * 64 + lane] = h;
    }
}

// ---- 5: one block per S1 row: compact match list -> parallel gather ->
//          x1 -> h2 -> ballot-driven agg2 contributions (global atomics)
__global__ __launch_bounds__(256) void k_x1agg(
        const int* __restrict__ cnts, const int2* __restrict__ L1,
        const int2* __restrict__ L2, const int* __restrict__ S1,
        const int* __restrict__ slot1, const int* __restrict__ slot2,
        const int* __restrict__ degc,
        const float* __restrict__ x0c, const float* __restrict__ h1c,
        const float* __restrict__ g1b, const float* __restrict__ ln1w,
        const float* __restrict__ ln1b, const float* __restrict__ g2w,
        float* __restrict__ agg2, float* __restrict__ x1c3) {
    __shared__ int   s_cnt;
    __shared__ int   s_ea[XB_LIST];
    __shared__ float s_ew[XB_LIST];
    __shared__ float s_part[4][64];
    int t = threadIdx.x, lane = t & 63, wid = t >> 6, b = blockIdx.x;
    int nl1 = min(cnts[0], MAXL1);
    int ns1 = min(cnts[1], MAXS1);
    int nl2 = min(cnts[2], MAXL2);
    if (b >= ns1) return;
    if (t == 0) s_cnt = 0;
    s_part[wid][lane] = 0.f;
    __syncthreads();
    int n = S1[b];                   // this block's node
    int sc2 = slot2[n];              // its S2 slot (S1 subset of S2)
    float dc = rsqrtf((float)(degc[sc2] + 1));
    // resolve: thread-parallel scan of L2 + S1 self-loops, compact matches
    int ntot = nl2 + ns1;
    for (int e = t; e < ntot; e += 256) {
        int r; bool match;
        if (e < nl2) { int2 rc = L2[e]; r = rc.x; match = (slot1[rc.y] == b); }
        else         { r = S1[e - nl2]; match = (e - nl2 == b); }   // self loop
        if (match) {
            int a = slot2[r];
            if ((unsigned)a < MAXS2) {
                float w = rsqrtf((float)(degc[a] + 1)) * dc;
                int m = atomicAdd(&s_cnt, 1);
                if (m < XB_LIST) { s_ea[m] = a; s_ew[m] = w; }
            }
        }
    }
    __syncthreads();
    // accumulate: 4 waves, independent coalesced gathers, wave-private partials
    int cm = min(s_cnt, XB_LIST);
    for (int m = wid; m < cm; m += 4)
        s_part[wid][lane] += h1c[s_ea[m] * 64 + lane] * s_ew[m];
    __syncthreads();
    if (wid == 0) {
        float agg = s_part[0][lane] + s_part[1][lane] + s_part[2][lane] + s_part[3][lane];
        float v = x0c[sc2 * 64 + lane] + agg + g1b[lane];
        float sum = wave_sum64(v), sq = wave_sum64(v * v);
        float mean = sum * (1.f / 64.f);
        float var = sq * (1.f / 64.f) - mean * mean;
        float x1 = (v - mean) * rsqrtf(var + 1e-5f) * ln1w[lane] + ln1b[lane];
        if (n < 3) x1c3[n * 64 + lane] = x1;
        // h2 = x1 @ gcn2_w (row-local)
        float h = 0.f;
#pragma unroll
        for (int j = 0; j < 64; j++) {
            float xj = __shfl(x1, j, 64);
            h = fmaf(xj, g2w[j * 64 + lane], h);
        }
        // agg2 contributions: edges in L1 (+{0,1,2} self-loops) whose row == n
        int ntot2 = nl1 + 3;
        for (int e0 = 0; e0 < ntot2; e0 += 64) {
            int e = e0 + lane;
            int match = 0, cc = 0; float wgt = 0.f;
            if (e < ntot2) {
                int r, c;
                if (e < nl1) { int2 rc = L1[e]; r = rc.x; c = rc.y; }
                else { r = c = e - nl1; }   // self loops for 0,1,2
                if (slot1[r] == b) {
                    int sr2 = slot2[r], scc2 = slot2[c];
                    if ((unsigned)sr2 < MAXS2 && (unsigned)scc2 < MAXS2) {
                        wgt = rsqrtf((float)(degc[sr2] + 1)) * rsqrtf((float)(degc[scc2] + 1));
                        match = 1; cc = c;
                    }
                }
            }
            unsigned long long msk = __ballot(match);
            while (msk) {
                int j = __ffsll((unsigned long long)msk) - 1;
                msk &= msk - 1;
                int cj = __shfl(cc, j, 64);
                float wj = __shfl(wgt, j, 64);
                atomicAdd(&agg2[cj * 64 + lane], h * wj);
            }
        }
    }
}

// ---- 6: x2+hg redundant per block, then 64-col GEMV slice (R8-measured-best)
__global__ __launch_bounds__(256) void k_out2(
        const float* __restrict__ x1c3, const float* __restrict__ agg2,
        const float* __restrict__ g2b, const float* __restrict__ ln2w,
        const float* __restrict__ ln2b,
        const float* __restrict__ w10, const float* __restrict__ b10,
        const float* __restrict__ w11, const float* __restrict__ b11,
        const float* __restrict__ w12, const float* __restrict__ b12,
        const float* __restrict__ w20, const float* __restrict__ b20,
        const float* __restrict__ w21, const float* __restrict__ b21,
        const float* __restrict__ w22, const float* __restrict__ b22,
        float* __restrict__ out) {
    __shared__ float s_x2[192];
    __shared__ float s_hg[768];
    __shared__ float part[256];
    int t = threadIdx.x, lane = t & 63, wid = t >> 6;
    if (wid < 3) {
        float v = x1c3[wid * 64 + lane] + agg2[wid * 64 + lane] + g2b[lane];
        float sum = wave_sum64(v), sq = wave_sum64(v * v);
        float mean = sum * (1.f / 64.f);
        float var = sq * (1.f / 64.f) - mean * mean;
        s_x2[wid * 64 + lane] = (v - mean) * rsqrtf(var + 1e-5f) * ln2w[lane] + ln2b[lane];
    }
    __syncthreads();
    {
        const float* W1[3] = {w10, w11, w12};
        const float* B1[3] = {b10, b11, b12};
#pragma unroll
        for (int gi = 0; gi < 3; gi++) {
            float acc = B1[gi][t];
#pragma unroll
            for (int j = 0; j < 64; j++) acc = fmaf(s_x2[gi * 64 + j], W1[gi][j * 256 + t], acc);
            s_hg[gi * 256 + t] = fmaxf(acc, 0.f);
        }
    }
    __syncthreads();
    int o = blockIdx.x * 64 + lane;
    int gi = -1, jj = 0, od = 1;
    const float* w2 = w20;
    if (o < OD0)                 { gi = 0; jj = o;             od = OD0; w2 = w20; }
    else if (o < OD0 + OD1)      { gi = 1; jj = o - OD0;       od = OD1; w2 = w21; }
    else if (o < OUT_TOTAL)      { gi = 2; jj = o - OD0 - OD1; od = OD2; w2 = w22; }
    float acc = 0.f;
    if (gi >= 0) {
        const float* h = &s_hg[gi * 256 + wid * 64];
        const float* wp = &w2[(size_t)(wid * 64) * od + jj];
#pragma unroll 16
        for (int k = 0; k < 64; k++) acc = fmaf(h[k], wp[(size_t)k * od], acc);
    }
    part[t] = acc;
    __syncthreads();
    if (t < 64 && gi >= 0) {
        float r = part[t] + part[t + 64] + part[t + 128] + part[t + 192];
        const float* b2 = (gi == 0) ? b20 : (gi == 1) ? b21 : b22;
        out[o] = r + b2[jj];
    }
}

extern "C" void kernel_launch(void* const* d_in, const int* in_sizes, int n_in,
                              void* d_out, int out_size, void* d_ws, size_t ws_size,
                              hipStream_t stream) {
    (void)in_sizes; (void)n_in; (void)out_size; (void)ws_size;
    const float* latent = (const float*)d_in[0];
    const int*   edges  = (const int*)d_in[1];
    const float* wq  = (const float*)d_in[2];
    const float* bq  = (const float*)d_in[3];
    const float* wk  = (const float*)d_in[4];
    const float* bk  = (const float*)d_in[5];
    const float* wv  = (const float*)d_in[6];
    const float* bv  = (const float*)d_in[7];
    const float* ln0w = (const float*)d_in[8];
    const float* ln0b = (const float*)d_in[9];
    const float* g1w  = (const float*)d_in[10];
    const float* g1b  = (const float*)d_in[11];
    const float* ln1w = (const float*)d_in[12];
    const float* ln1b = (const float*)d_in[13];
    const float* g2w  = (const float*)d_in[14];
    const float* g2b  = (const float*)d_in[15];
    const float* ln2w = (const float*)d_in[16];
    const float* ln2b = (const float*)d_in[17];
    const float* gw1_0 = (const float*)d_in[18];
    const float* gb1_0 = (const float*)d_in[19];
    const float* gw2_0 = (const float*)d_in[20];
    const float* gb2_0 = (const float*)d_in[21];
    const float* gw1_1 = (const float*)d_in[22];
    const float* gb1_1 = (const float*)d_in[23];
    const float* gw2_1 = (const float*)d_in[24];
    const float* gb2_1 = (const float*)d_in[25];
    const float* gw1_2 = (const float*)d_in[26];
    const float* gb1_2 = (const float*)d_in[27];
    const float* gw2_2 = (const float*)d_in[28];
    const float* gb2_2 = (const float*)d_in[29];

    // workspace carve: [cnts|mask1|mask2|degc|agg2] = zero region
    char* ptr = (char*)d_ws;
    auto alloc = [&](size_t bytes) { char* r = ptr; ptr += (bytes + 255) & ~(size_t)255; return r; };
    int*      cnts  = (int*)alloc(64 * 4);        // [0]=nL1 [1]=nS1 [2]=nL2 [3]=nS2
    unsigned* mask1 = (unsigned*)alloc(MASKW * 4);
    unsigned* mask2 = (unsigned*)alloc(MASKW * 4);
    int*      degc  = (int*)alloc((size_t)MAXS2 * 4);
    float*    agg2  = (float*)alloc(192 * 4);
    char*     zero_end = ptr;
    int*      slot1 = (int*)alloc((size_t)NN * 4);   // valid only where mask1 bit set
    int*      slot2 = (int*)alloc((size_t)NN * 4);   // valid only where mask2 bit set
    int2*     L1    = (int2*)alloc((size_t)MAXL1 * 8);
    int*      S1    = (int*)alloc((size_t)MAXS1 * 4);
    int2*     L2    = (int2*)alloc((size_t)MAXL2 * 8);
    int*      S2    = (int*)alloc((size_t)MAXS2 * 4);
    float*    x0c   = (float*)alloc((size_t)MAXS2 * 64 * 4);
    float*    h1c   = (float*)alloc((size_t)MAXS2 * 64 * 4);
    float*    x1c3  = (float*)alloc(192 * 4);

    const int* erow = edges;
    const int* ecol = edges + NE;
    int zero_n4 = (int)((zero_end - (char*)cnts) / 16);

    const int SCAN_GRID = (NQ + 255) / 256;   // 782 blocks, 2 int4-streams/thread
    k_init<<<16, 256, 0, stream>>>((int4*)cnts, zero_n4);
    k_scan1<<<SCAN_GRID, 256, 0, stream>>>(erow, ecol, cnts, mask1, slot1, S1, L1);
    k_scan2<<<SCAN_GRID, 256, 0, stream>>>(erow, ecol, cnts, mask1, mask2, slot2, S2, S1, L2);
    k_degx0<<<DX_GRID, 256, 0, stream>>>(cnts, ecol, mask2, slot2, degc, S2, latent,
                                         wq, bq, wk, bk, wv, bv, ln0w, ln0b, g1w, x0c, h1c);
    k_x1agg<<<MAXS1, 256, 0, stream>>>(cnts, L1, L2, S1, slot1, slot2, degc, x0c, h1c,
                                       g1b, ln1w, ln1b, g2w, agg2, x1c3);
    k_out2<<<NB_OUT, 256, 0, stream>>>(x1c3, agg2, g2b, ln2w, ln2b,
                                       gw1_0, gb1_0, gw1_1, gb1_1, gw1_2, gb1_2,
                                       gw2_0, gb2_0, gw2_1, gb2_1, gw2_2, gb2_2,
                                       (float*)d_out);
}